// Round 15
// baseline (694.104 us; speedup 1.0000x reference)
//
#include <hip/hip_runtime.h>
#include <hip/hip_fp16.h>
#include <math.h>

// ---------------------------------------------------------------------------
// GAT x3 + BN on MI355X.
//   R23 = R21 (682us verified best) + gemm grid = exact tile count.
//   R22 post-mortem: int8 hb (per-row amax) FAILED accuracy — absmax 1.05 >
//   0.49 (error compounds ~2x/layer through 3 layers; bf16 baseline 0.39
//   leaves no headroom for 2x quantization). Table compression closed.
//   Rider: k_gemm3 previously ran 782 tiles on 512 blocks -> 2 tile-passes
//   with half the machine idle in pass 2; LDS 53KB/block = 3 blocks/CU =
//   768 resident, so grid=ntiles (782) is ~1 pass.
//   Kept: NB=64 u8 histograms, BN-fold in gemm3, in-loop alpha agg (R18),
//   bf16 MFMA gemm (R17). Aggregator floor (8 falsifications incl. int8)
//   accepted at ~124us/dispatch.
//   (R24 resubmit: R23 bench was an infra failure — container died twice.)
// ---------------------------------------------------------------------------

#define NB 64  // blocks for hist/scatter (same partition in both)

typedef __attribute__((ext_vector_type(8))) short bf16x8;
typedef __attribute__((ext_vector_type(4))) float f32x4;

__device__ __forceinline__ unsigned short f2bf(float x) {
  unsigned u = __float_as_uint(x);
  unsigned r = (u + 0x7FFFu + ((u >> 16) & 1u)) >> 16;  // RNE
  return (unsigned short)r;
}
__device__ __forceinline__ float bf_lo(unsigned u) { return __uint_as_float(u << 16); }
__device__ __forceinline__ float bf_hi(unsigned u) { return __uint_as_float(u & 0xFFFF0000u); }

// NB blocks; private u8-packed LDS histogram + ea column sums
__global__ void k_hist_lds(const int* __restrict__ dst, const float* __restrict__ ea, int E,
                           int n, unsigned* __restrict__ hist32, float* __restrict__ ea_sum) {
  extern __shared__ unsigned cnt[];
  int nh4 = (n + 3) >> 2;
  for (int i = threadIdx.x; i < nh4; i += blockDim.x) cnt[i] = 0u;
  __syncthreads();
  int tid = blockIdx.x * blockDim.x + threadIdx.x;
  int stride = gridDim.x * blockDim.x;
  float s0 = 0.f, s1 = 0.f, s2 = 0.f;
  for (int i = tid; i < E; i += stride) {
    int d = dst[i];
    atomicAdd(&cnt[d >> 2], 1u << ((d & 3) << 3));
    s0 += ea[i * 3 + 0]; s1 += ea[i * 3 + 1]; s2 += ea[i * 3 + 2];
  }
  for (int off = 32; off; off >>= 1) {
    s0 += __shfl_down(s0, off); s1 += __shfl_down(s1, off); s2 += __shfl_down(s2, off);
  }
  if ((threadIdx.x & 63) == 0) {
    atomicAdd(&ea_sum[0], s0); atomicAdd(&ea_sum[1], s1); atomicAdd(&ea_sum[2], s2);
  }
  __syncthreads();
  unsigned* plane = hist32 + (size_t)blockIdx.x * nh4;
  for (int i = threadIdx.x; i < nh4; i += blockDim.x) plane[i] = cnt[i];
}

__device__ __forceinline__ int wave_incl_scan(int x, int lane) {
  for (int off = 1; off < 64; off <<= 1) {
    int t = __shfl_up(x, off);
    if (lane >= off) x += t;
  }
  return x;
}

// phase A: sum NB u8 planes -> per-block exclusive scan -> start[], block sums
__global__ __launch_bounds__(1024) void k_scan_a(const unsigned* __restrict__ hist32, int n,
                                                 int* __restrict__ start,
                                                 int* __restrict__ bsum) {
  __shared__ int wsum[16];
  int t = threadIdx.x, lane = t & 63, w = t >> 6;
  int i = blockIdx.x * 1024 + t;
  int nh4 = (n + 3) >> 2;
  size_t planeB = (size_t)nh4 * 4;
  const unsigned char* h8 = (const unsigned char*)hist32;
  int v = 0;
  if (i < n) {
#pragma unroll 8
    for (int r = 0; r < NB; ++r) v += h8[(size_t)r * planeB + i];
  }
  int x = wave_incl_scan(v, lane);
  if (lane == 63) wsum[w] = x;
  __syncthreads();
  if (w == 0 && lane < 16) {
    int s = wsum[lane];
    for (int off = 1; off < 16; off <<= 1) {
      int u = __shfl_up(s, off);
      if (lane >= off) s += u;
    }
    wsum[lane] = s;
  }
  __syncthreads();
  int woff = w ? wsum[w - 1] : 0;
  if (i < n) start[i] = x - v + woff;
  if (t == 1023) bsum[blockIdx.x] = wsum[15];
}

__global__ void k_scan_b(int* __restrict__ bsum, int nb, int* __restrict__ start, int n) {
  int lane = threadIdx.x;  // 64
  int v = (lane < nb) ? bsum[lane] : 0;
  int x = wave_incl_scan(v, lane);
  if (lane < nb) bsum[lane] = x - v;
  if (lane == nb - 1) start[n] = x;
}

// phase C: finalize start; emit per-(block,node) cursor bases
__global__ void k_scan_c(int* __restrict__ start, const int* __restrict__ bsum,
                         const unsigned* __restrict__ hist32, int n,
                         int* __restrict__ cursorp) {
  int i = blockIdx.x * blockDim.x + threadIdx.x;
  if (i >= n) return;
  int nh4 = (n + 3) >> 2;
  size_t planeB = (size_t)nh4 * 4;
  const unsigned char* h8 = (const unsigned char*)hist32;
  int s = start[i] + bsum[i >> 10];
  start[i] = s;
  int run = s;
#pragma unroll 8
  for (int r = 0; r < NB; ++r) {
    cursorp[(size_t)r * n + i] = run;
    run += h8[(size_t)r * planeB + i];
  }
}

// same NB-block edge partition as hist; rank via LDS packed-u8 atomic;
// writes three 8B records {src, eaP_l} per edge (eaP in fp32 from raw ea).
__global__ void k_scatter_lds(const int* __restrict__ src, const int* __restrict__ dst,
                              const float* __restrict__ ea, int E, int n,
                              const int* __restrict__ cursorp,
                              const float* __restrict__ P_all,
                              int2* __restrict__ m0a, int2* __restrict__ m1a,
                              int2* __restrict__ m2a) {
  extern __shared__ unsigned cnt[];
  int nh4 = (n + 3) >> 2;
  for (int i = threadIdx.x; i < nh4; i += blockDim.x) cnt[i] = 0u;
  __syncthreads();
  float P00 = P_all[0], P01 = P_all[1], P02 = P_all[2];
  float P10 = P_all[4], P11 = P_all[5], P12 = P_all[6];
  float P20 = P_all[8], P21 = P_all[9], P22 = P_all[10];
  const int* cur = cursorp + (size_t)blockIdx.x * n;
  int tid = blockIdx.x * blockDim.x + threadIdx.x;
  int stride = gridDim.x * blockDim.x;
  for (int i = tid; i < E; i += stride) {
    int d = dst[i];
    int sh = (d & 3) << 3;
    unsigned old = atomicAdd(&cnt[d >> 2], 1u << sh);
    int rank = (old >> sh) & 0xFF;
    int pos = cur[d] + rank;
    float e0 = ea[i * 3 + 0], e1 = ea[i * 3 + 1], e2 = ea[i * 3 + 2];
    int s = src[i];
    int2 r;
    r.x = s;
    r.y = __float_as_int(e0 * P00 + e1 * P01 + e2 * P02);
    m0a[pos] = r;
    r.y = __float_as_int(e0 * P10 + e1 * P11 + e2 * P12);
    m1a[pos] = r;
    r.y = __float_as_int(e0 * P20 + e1 * P21 + e2 * P22);
    m2a[pos] = r;
  }
}

__device__ __forceinline__ void param_wave(const float* __restrict__ We,
                                           const float* __restrict__ ae,
                                           const float* __restrict__ ea_sum, float invE,
                                           float* __restrict__ P, int lane) {
  float a0 = ae[lane], a1 = ae[64 + lane];
  float p0 = We[0 * 128 + lane] * a0 + We[0 * 128 + 64 + lane] * a1;
  float p1 = We[1 * 128 + lane] * a0 + We[1 * 128 + 64 + lane] * a1;
  float p2 = We[2 * 128 + lane] * a0 + We[2 * 128 + 64 + lane] * a1;
  for (int off = 32; off; off >>= 1) {
    p0 += __shfl_down(p0, off); p1 += __shfl_down(p1, off); p2 += __shfl_down(p2, off);
  }
  if (lane == 0) {
    P[0] = p0; P[1] = p1; P[2] = p2;
    P[3] = ea_sum[0] * invE * p0 + ea_sum[1] * invE * p1 + ea_sum[2] * invE * p2;
  }
}

// all three layers' P vectors (wave l -> P_all[4l..4l+3]) + zero cs0/1/2
__global__ void k_param_all(const float* __restrict__ We0, const float* __restrict__ ae0,
                            const float* __restrict__ We1, const float* __restrict__ ae1,
                            const float* __restrict__ We2, const float* __restrict__ ae2,
                            const float* __restrict__ ea_sum, float invE,
                            float* __restrict__ P_all, float* __restrict__ cs0,
                            float* __restrict__ cs1, float* __restrict__ cs2) {
  int t = threadIdx.x;  // 256
  if (t < 192) {
    int l = t >> 6, lane = t & 63;
    const float* We = l == 0 ? We0 : l == 1 ? We1 : We2;
    const float* ae = l == 0 ? ae0 : l == 1 ? ae1 : ae2;
    param_wave(We, ae, ea_sum, invE, P_all + 4 * l, lane);
  } else {
    for (int i = t - 192; i < 256; i += 64) {
      cs0[i] = 0.f; cs1[i] = 0.f; cs2[i] = 0.f;
    }
  }
}

// h[N,128] = BN(X) @ W via bf16 MFMA.  BN scale/shift computed IN-KERNEL
// from csIn (colstats of previous layer; csIn==null -> identity).
__global__ __launch_bounds__(256) void k_gemm3(
    const float* __restrict__ X, const float* __restrict__ Wm,
    const float* __restrict__ csIn, const float* __restrict__ g,
    const float* __restrict__ be, float invN,
    const float* __restrict__ as, const float* __restrict__ ad,
    const float* __restrict__ P,
    unsigned* __restrict__ hb, float* __restrict__ al_s, float* __restrict__ al_d,
    float* __restrict__ es, int n) {
  __shared__ __align__(16) unsigned short wb[128 * 136];  // 34.8 KB
  __shared__ __align__(16) unsigned short xb[64 * 136];   // 17.4 KB
  __shared__ float sc_s[128], sh_s[128];
  int t = threadIdx.x;
  int lane = t & 63;
  int w = t >> 6;
  int c16 = lane & 15;
  int kq = lane >> 4;
  if (t < 128) {
    float sc = 1.f, sh = 0.f;
    if (csIn) {
      float mu = csIn[t] * invN;
      float var = csIn[128 + t] * invN - mu * mu;
      var = var > 0.f ? var : 0.f;
      sc = g[t] * rsqrtf(var + 1e-5f);
      sh = be[t] - mu * sc;
    }
    sc_s[t] = sc; sh_s[t] = sh;
  }
  for (int i = t; i < 4096; i += 256) {
    int k = i >> 5, c4 = (i & 31) << 2;
    float4 v = ((const float4*)(Wm + k * 128))[i & 31];
    wb[(c4 + 0) * 136 + k] = f2bf(v.x);
    wb[(c4 + 1) * 136 + k] = f2bf(v.y);
    wb[(c4 + 2) * 136 + k] = f2bf(v.z);
    wb[(c4 + 3) * 136 + k] = f2bf(v.w);
  }
  float asv[8], adv[8];
#pragma unroll
  for (int ct = 0; ct < 8; ++ct) {
    asv[ct] = as[ct * 16 + c16];
    adv[ct] = ad[ct * 16 + c16];
  }
  float cself = P[3];
  int ntiles = (n + 63) >> 6;
  for (int tile = blockIdx.x; tile < ntiles; tile += gridDim.x) {
    int r0 = tile << 6;
    __syncthreads();  // protect xb vs prev epilogue; publish sc_s/sh_s/wb
    for (int i = t; i < 2048; i += 256) {
      int row = i >> 5, c4 = i & 31;
      int g2 = r0 + row;
      float4 v;
      if (g2 < n) {
        v = ((const float4*)(X + (size_t)g2 * 128))[c4];
        float4 sc = ((const float4*)sc_s)[c4];
        float4 sh = ((const float4*)sh_s)[c4];
        v.x = fmaf(v.x, sc.x, sh.x); v.y = fmaf(v.y, sc.y, sh.y);
        v.z = fmaf(v.z, sc.z, sh.z); v.w = fmaf(v.w, sc.w, sh.w);
      } else { v.x = v.y = v.z = v.w = 0.f; }
      uint2 pk;
      pk.x = (unsigned)f2bf(v.x) | ((unsigned)f2bf(v.y) << 16);
      pk.y = (unsigned)f2bf(v.z) | ((unsigned)f2bf(v.w) << 16);
      *(uint2*)(xb + row * 136 + (c4 << 2)) = pk;
    }
    __syncthreads();
    const unsigned short* xr = xb + (w * 16 + c16) * 136 + kq * 8;
    bf16x8 A[4];
#pragma unroll
    for (int kb = 0; kb < 4; ++kb) A[kb] = *(const bf16x8*)(xr + kb * 32);
    f32x4 acc[8];
#pragma unroll
    for (int ct = 0; ct < 8; ++ct) {
      const unsigned short* wr = wb + (ct * 16 + c16) * 136 + kq * 8;
      f32x4 a = {0.f, 0.f, 0.f, 0.f};
#pragma unroll
      for (int kb = 0; kb < 4; ++kb) {
        bf16x8 B = *(const bf16x8*)(wr + kb * 32);
        a = __builtin_amdgcn_mfma_f32_16x16x32_bf16(A[kb], B, a, 0, 0, 0);
      }
      acc[ct] = a;
    }
#pragma unroll
    for (int r = 0; r < 4; ++r) {
      int R = kq * 4 + r;
      float pr = 0.f, pd = 0.f;
#pragma unroll
      for (int ct = 0; ct < 8; ++ct) {
        float hv = acc[ct][r];
        xb[(w * 16 + R) * 136 + ct * 16 + c16] = f2bf(hv);
        pr = fmaf(hv, asv[ct], pr);
        pd = fmaf(hv, adv[ct], pd);
      }
      for (int off = 8; off; off >>= 1) {
        pr += __shfl_xor(pr, off);
        pd += __shfl_xor(pd, off);
      }
      int g2 = r0 + w * 16 + R;
      if (c16 == 0 && g2 < n) {
        al_s[g2] = pr; al_d[g2] = pd;
        float a = pr + pd + cself;
        a = a > 0.f ? a : 0.2f * a;
        es[g2] = __expf(a);
      }
    }
    __syncthreads();  // ensure LDS h visible (cross-lane) before flush
    for (int i = lane; i < 256; i += 64) {
      int row = i >> 4, cc = i & 15;
      int g2 = r0 + w * 16 + row;
      if (g2 < n) {
        uint4 v = *(const uint4*)(xb + (w * 16 + row) * 136 + (cc << 3));
        *(uint4*)(hb + (size_t)g2 * 64 + (cc << 2)) = v;
      }
    }
  }
}

// One wave per node; 16-lane x uint4 row gathers (4 edges/instruction) with
// in-loop alpha (R18, verified: exp hides under gather fill).
__global__ __launch_bounds__(256) void k_agg11(const int2* __restrict__ meta,
                                               const int* __restrict__ start,
                                               const unsigned* __restrict__ hb,
                                               const float* __restrict__ es,
                                               const float* __restrict__ al_s,
                                               const float* __restrict__ al_d,
                                               const float* __restrict__ bias,
                                               float* __restrict__ y,
                                               float* __restrict__ colsum,
                                               float* __restrict__ colsumsq, int n) {
  int lane = threadIdx.x & 63;
  int w = threadIdx.x >> 6;
  int grp = lane >> 4;   // 0..3: which edge of the quad this lane serves
  int sub = lane & 15;   // position within the row (16 lanes x 16B = 256B)
  int gw = (blockIdx.x * blockDim.x + threadIdx.x) >> 6;
  int nw = (gridDim.x * blockDim.x) >> 6;
  int c0 = (sub << 3) + (grp << 1);  // this lane's 2 output cols
  float2 b2 = ((const float2*)bias)[(sub << 2) + grp];
  float s0 = 0.f, s1 = 0.f, q0 = 0.f, q1 = 0.f;

#define DO_QUAD(EB)                                                          \
  {                                                                          \
    int i0 = (EB), i1 = (EB) + 1, i2 = (EB) + 2, i3 = (EB) + 3;              \
    int2 m0 = meta[i0 < e1 ? i0 : e0];                                       \
    int2 m1 = meta[i1 < e1 ? i1 : e0];                                       \
    int2 m2 = meta[i2 < e1 ? i2 : e0];                                       \
    int2 m3 = meta[i3 < e1 ? i3 : e0];                                       \
    int r0 = i0 < e1 ? m0.x : i;                                             \
    int r1 = i1 < e1 ? m1.x : i;                                             \
    int r2 = i2 < e1 ? m2.x : i;                                             \
    int r3 = i3 < e1 ? m3.x : i;                                             \
    float a0 = al_s[r0] + ad_i + __int_as_float(m0.y);                       \
    float a1 = al_s[r1] + ad_i + __int_as_float(m1.y);                       \
    float a2 = al_s[r2] + ad_i + __int_as_float(m2.y);                       \
    float a3 = al_s[r3] + ad_i + __int_as_float(m3.y);                       \
    a0 = a0 > 0.f ? a0 : 0.2f * a0;                                          \
    a1 = a1 > 0.f ? a1 : 0.2f * a1;                                          \
    a2 = a2 > 0.f ? a2 : 0.2f * a2;                                          \
    a3 = a3 > 0.f ? a3 : 0.2f * a3;                                          \
    float p0 = i0 < e1 ? __expf(a0) : 0.f;                                   \
    float p1 = i1 < e1 ? __expf(a1) : 0.f;                                   \
    float p2 = i2 < e1 ? __expf(a2) : 0.f;                                   \
    float p3 = i3 < e1 ? __expf(a3) : 0.f;                                   \
    int rr = grp == 0 ? r0 : grp == 1 ? r1 : grp == 2 ? r2 : r3;             \
    float pp = grp == 0 ? p0 : grp == 1 ? p1 : grp == 2 ? p2 : p3;           \
    uint4 gv = *(const uint4*)(hb + (size_t)rr * 64 + (sub << 2));           \
    pacc += (p0 + p1) + (p2 + p3);                                           \
    aL0 = fmaf(pp, bf_lo(gv.x), aL0); aH0 = fmaf(pp, bf_hi(gv.x), aH0);      \
    aL1 = fmaf(pp, bf_lo(gv.y), aL1); aH1 = fmaf(pp, bf_hi(gv.y), aH1);      \
    aL2 = fmaf(pp, bf_lo(gv.z), aL2); aH2 = fmaf(pp, bf_hi(gv.z), aH2);      \
    aL3 = fmaf(pp, bf_lo(gv.w), aL3); aH3 = fmaf(pp, bf_hi(gv.w), aH3);      \
  }

  for (int i = gw; i < n; i += nw) {
    int e0 = __builtin_amdgcn_readfirstlane(start[i]);
    int e1 = __builtin_amdgcn_readfirstlane(start[i + 1]);
    float eself = es[i];
    float ad_i = al_d[i];
    uint4 hv = *(const uint4*)(hb + (size_t)i * 64 + (sub << 2));
    float wself = (grp == 0) ? eself : 0.f;  // self-term counted once
    float aL0 = wself * bf_lo(hv.x), aH0 = wself * bf_hi(hv.x);
    float aL1 = wself * bf_lo(hv.y), aH1 = wself * bf_hi(hv.y);
    float aL2 = wself * bf_lo(hv.z), aH2 = wself * bf_hi(hv.z);
    float aL3 = wself * bf_lo(hv.w), aH3 = wself * bf_hi(hv.w);
    float pacc = 0.f;
    int e = e0;
    for (; e + 8 <= e1; e += 8) {  // two quads -> two gathers in flight
      DO_QUAD(e);
      DO_QUAD(e + 4);
    }
    for (; e < e1; e += 4) DO_QUAD(e);
    // combine the 4 lane-groups (bits 4,5 of lane)
    aL0 += __shfl_xor(aL0, 16); aL0 += __shfl_xor(aL0, 32);
    aH0 += __shfl_xor(aH0, 16); aH0 += __shfl_xor(aH0, 32);
    aL1 += __shfl_xor(aL1, 16); aL1 += __shfl_xor(aL1, 32);
    aH1 += __shfl_xor(aH1, 16); aH1 += __shfl_xor(aH1, 32);
    aL2 += __shfl_xor(aL2, 16); aL2 += __shfl_xor(aL2, 32);
    aH2 += __shfl_xor(aH2, 16); aH2 += __shfl_xor(aH2, 32);
    aL3 += __shfl_xor(aL3, 16); aL3 += __shfl_xor(aL3, 32);
    aH3 += __shfl_xor(aH3, 16); aH3 += __shfl_xor(aH3, 32);
    float inv = 1.0f / (eself + pacc + 1e-16f);
    float o0 = grp == 0 ? aL0 : grp == 1 ? aL1 : grp == 2 ? aL2 : aL3;
    float o1 = grp == 0 ? aH0 : grp == 1 ? aH1 : grp == 2 ? aH2 : aH3;
    o0 = fmaf(o0, inv, b2.x);
    o1 = fmaf(o1, inv, b2.y);
    o0 = o0 > 0.f ? o0 : 0.01f * o0;
    o1 = o1 > 0.f ? o1 : 0.01f * o1;
    float2 o2 = {o0, o1};
    *(float2*)(y + (size_t)i * 128 + c0) = o2;
    s0 += o0; s1 += o1;
    q0 = fmaf(o0, o0, q0); q1 = fmaf(o1, o1, q1);
  }
#undef DO_QUAD
  __shared__ float red[4][4][64];
  red[0][w][lane] = s0; red[1][w][lane] = s1; red[2][w][lane] = q0; red[3][w][lane] = q1;
  __syncthreads();
  if (w == 0) {
    for (int ww = 1; ww < 4; ++ww) {
      s0 += red[0][ww][lane]; s1 += red[1][ww][lane];
      q0 += red[2][ww][lane]; q1 += red[3][ww][lane];
    }
    atomicAdd(&colsum[c0], s0);
    atomicAdd(&colsum[c0 + 1], s1);
    atomicAdd(&colsumsq[c0], q0);
    atomicAdd(&colsumsq[c0 + 1], q1);
  }
}

// final BN: compute scale/shift from colstats in-block, then apply y -> out
__global__ __launch_bounds__(256) void k_bnapply_final(
    const float4* __restrict__ yin, const float* __restrict__ colstats,
    const float* __restrict__ g, const float* __restrict__ be, float invN,
    float4* __restrict__ yout, int total4) {
  __shared__ float sc_s[128], sh_s[128];
  int t = threadIdx.x;
  if (t < 128) {
    float mu = colstats[t] * invN;
    float var = colstats[128 + t] * invN - mu * mu;
    var = var > 0.f ? var : 0.f;
    float sc = g[t] * rsqrtf(var + 1e-5f);
    sc_s[t] = sc;
    sh_s[t] = be[t] - mu * sc;
  }
  __syncthreads();
  for (int i = blockIdx.x * blockDim.x + t; i < total4; i += gridDim.x * blockDim.x) {
    int c4 = (i & 31) << 2;
    float4 v = yin[i];
    v.x = fmaf(v.x, sc_s[c4 + 0], sh_s[c4 + 0]);
    v.y = fmaf(v.y, sc_s[c4 + 1], sh_s[c4 + 1]);
    v.z = fmaf(v.z, sc_s[c4 + 2], sh_s[c4 + 2]);
    v.w = fmaf(v.w, sc_s[c4 + 3], sh_s[c4 + 3]);
    yout[i] = v;
  }
}

extern "C" void kernel_launch(void* const* d_in, const int* in_sizes, int n_in,
                              void* d_out, int out_size, void* d_ws, size_t ws_size,
                              hipStream_t stream) {
  const float* x = (const float*)d_in[0];
  const int* eidx = (const int*)d_in[1];
  const float* ea = (const float*)d_in[3];
  const int H = 128;
  const int N = in_sizes[0] / H;
  const int E = in_sizes[1] / 2;
  const int* srcIdx = eidx;
  const int* dstIdx = eidx + E;
  const int nh4 = (N + 3) >> 2;

  char* ws = (char*)d_ws;
  size_t off = 0;
  auto alloc = [&](size_t bytes) -> void* {
    void* p = ws + off;
    off = (off + bytes + 255) & ~(size_t)255;
    return p;
  };
  int2* meta0 = (int2*)alloc((size_t)E * sizeof(int2));  // {src, eaP0}
  int2* meta1 = (int2*)alloc((size_t)E * sizeof(int2));  // {src, eaP1}
  int2* meta2 = (int2*)alloc((size_t)E * sizeof(int2));  // {src, eaP2}
  unsigned* hb = (unsigned*)alloc((size_t)N * 64 * sizeof(unsigned));  // bf16 h
  float* y = (float*)alloc((size_t)N * H * sizeof(float));
  float* al_s = (float*)alloc((size_t)N * sizeof(float));
  float* al_d = (float*)alloc((size_t)N * sizeof(float));
  float* es = (float*)alloc((size_t)N * sizeof(float));
  int* start = (int*)alloc((size_t)(N + 1) * sizeof(int));
  int* bsum = (int*)alloc(64 * sizeof(int));
  float* cs0 = (float*)alloc(256 * sizeof(float));
  float* cs1 = (float*)alloc(256 * sizeof(float));
  float* cs2 = (float*)alloc(256 * sizeof(float));
  float* ea_sum = (float*)alloc(64 * sizeof(float));
  float* P_all = (float*)alloc(16 * sizeof(float));
  unsigned* hist32 = (unsigned*)alloc((size_t)NB * nh4 * sizeof(unsigned));
  int* cursorp = (int*)alloc((size_t)NB * N * sizeof(int));

  const int nb = (N + 1023) / 1024;  // <= 64 scan_a blocks
  const float invE = 1.0f / (float)E;
  const float invN = 1.0f / (float)N;
  const size_t ldsBytes = (size_t)nh4 * sizeof(unsigned);  // ~50 KB @ N=50k
  const int ntiles = (N + 63) >> 6;  // gemm grid = exact tile count

  // layer parameter pointers
  const float* Wl[3]; const float* asl[3]; const float* adl[3]; const float* Wel[3];
  const float* ael[3]; const float* bl[3]; const float* gl[3]; const float* bel[3];
  for (int l = 0; l < 3; ++l) {
    Wl[l] = (const float*)d_in[4 + 8 * l + 0];
    asl[l] = (const float*)d_in[4 + 8 * l + 1];
    adl[l] = (const float*)d_in[4 + 8 * l + 2];
    Wel[l] = (const float*)d_in[4 + 8 * l + 3];
    ael[l] = (const float*)d_in[4 + 8 * l + 4];
    bl[l] = (const float*)d_in[4 + 8 * l + 5];
    gl[l] = (const float*)d_in[4 + 8 * l + 6];
    bel[l] = (const float*)d_in[4 + 8 * l + 7];
  }

  // ---- setup: CSR sort (u8 LDS histograms, NB=64 blocks); all-layer P ----
  hipMemsetAsync(ea_sum, 0, 64 * sizeof(float), stream);
  k_hist_lds<<<NB, 256, ldsBytes, stream>>>(dstIdx, ea, E, N, hist32, ea_sum);
  k_param_all<<<1, 256, 0, stream>>>(Wel[0], ael[0], Wel[1], ael[1], Wel[2], ael[2],
                                     ea_sum, invE, P_all, cs0, cs1, cs2);
  k_scan_a<<<nb, 1024, 0, stream>>>(hist32, N, start, bsum);
  k_scan_b<<<1, 64, 0, stream>>>(bsum, nb, start, N);
  k_scan_c<<<(N + 255) / 256, 256, 0, stream>>>(start, bsum, hist32, N, cursorp);
  k_scatter_lds<<<NB, 256, ldsBytes, stream>>>(srcIdx, dstIdx, ea, E, N, cursorp,
                                               P_all, meta0, meta1, meta2);

  int2* metas[3] = {meta0, meta1, meta2};
  float* css[3] = {cs0, cs1, cs2};
  const float* X = x;
  for (int l = 0; l < 3; ++l) {
    const float* csIn = l ? css[l - 1] : nullptr;
    const float* gIn = l ? gl[l - 1] : nullptr;
    const float* beIn = l ? bel[l - 1] : nullptr;
    k_gemm3<<<ntiles, 256, 0, stream>>>(X, Wl[l], csIn, gIn, beIn, invN,
                                        asl[l], adl[l], P_all + 4 * l,
                                        hb, al_s, al_d, es, N);
    k_agg11<<<2048, 256, 0, stream>>>(metas[l], start, hb, es, al_s, al_d, bl[l], y,
                                      css[l], css[l] + 128, N);
    X = y;
  }
  k_bnapply_final<<<384, 256, 0, stream>>>((const float4*)y, cs2, gl[2], bel[2], invN,
                                           (float4*)d_out, N * 32);
}

// Round 16
// 678.623 us; speedup vs baseline: 1.0228x; 1.0228x over previous
//
#include <hip/hip_runtime.h>
#include <hip/hip_fp16.h>
#include <math.h>

// ---------------------------------------------------------------------------
// GAT x3 + BN on MI355X.  FINAL (R25) = R21 verified-best config (682us).
//   R23/R24 post-mortem: gemm grid=ntiles (782) regressed to 694 — each
//   block pays the W-staging fixed cost (64KB->bf16 LDS transpose) once, so
//   512 blocks x ~1.5 tiles amortizes better; 782>768-resident also leaves
//   a 14-block full-pass tail. Grid reverted to 512.
//   Session summary (753 -> 682us):
//   - k_gemm3: bf16 MFMA (mfma_f32_16x16x32_bf16) + fused BN-in + fused
//     al_s/al_d/es epilogue (R17/R20).
//   - alpha pass deleted: per-edge exp/lrelu fused into aggregator; eaP
//     precomputed per layer into meta records at scatter (R18).
//   - k_agg11 floor ACCEPTED at ~124.5us/dispatch after 8 falsifications
//     (VMEM count x2, wave ILP x2, L1 bypass sc0, src-chunking, NT hints,
//     int8 table [accuracy fail 1.05>0.49]): bound by per-XCD L2 random
//     fill service on the 12.8MB bf16 h-table (FETCH 94MB/dispatch).
//   - setup: LDS-atomic CSR sort, u8-packed histograms, NB=64 (256
//     regressed: scan work scales with plane count).
// ---------------------------------------------------------------------------

#define NB 64  // blocks for hist/scatter (same partition in both)

typedef __attribute__((ext_vector_type(8))) short bf16x8;
typedef __attribute__((ext_vector_type(4))) float f32x4;

__device__ __forceinline__ unsigned short f2bf(float x) {
  unsigned u = __float_as_uint(x);
  unsigned r = (u + 0x7FFFu + ((u >> 16) & 1u)) >> 16;  // RNE
  return (unsigned short)r;
}
__device__ __forceinline__ float bf_lo(unsigned u) { return __uint_as_float(u << 16); }
__device__ __forceinline__ float bf_hi(unsigned u) { return __uint_as_float(u & 0xFFFF0000u); }

// NB blocks; private u8-packed LDS histogram + ea column sums
__global__ void k_hist_lds(const int* __restrict__ dst, const float* __restrict__ ea, int E,
                           int n, unsigned* __restrict__ hist32, float* __restrict__ ea_sum) {
  extern __shared__ unsigned cnt[];
  int nh4 = (n + 3) >> 2;
  for (int i = threadIdx.x; i < nh4; i += blockDim.x) cnt[i] = 0u;
  __syncthreads();
  int tid = blockIdx.x * blockDim.x + threadIdx.x;
  int stride = gridDim.x * blockDim.x;
  float s0 = 0.f, s1 = 0.f, s2 = 0.f;
  for (int i = tid; i < E; i += stride) {
    int d = dst[i];
    atomicAdd(&cnt[d >> 2], 1u << ((d & 3) << 3));
    s0 += ea[i * 3 + 0]; s1 += ea[i * 3 + 1]; s2 += ea[i * 3 + 2];
  }
  for (int off = 32; off; off >>= 1) {
    s0 += __shfl_down(s0, off); s1 += __shfl_down(s1, off); s2 += __shfl_down(s2, off);
  }
  if ((threadIdx.x & 63) == 0) {
    atomicAdd(&ea_sum[0], s0); atomicAdd(&ea_sum[1], s1); atomicAdd(&ea_sum[2], s2);
  }
  __syncthreads();
  unsigned* plane = hist32 + (size_t)blockIdx.x * nh4;
  for (int i = threadIdx.x; i < nh4; i += blockDim.x) plane[i] = cnt[i];
}

__device__ __forceinline__ int wave_incl_scan(int x, int lane) {
  for (int off = 1; off < 64; off <<= 1) {
    int t = __shfl_up(x, off);
    if (lane >= off) x += t;
  }
  return x;
}

// phase A: sum NB u8 planes -> per-block exclusive scan -> start[], block sums
__global__ __launch_bounds__(1024) void k_scan_a(const unsigned* __restrict__ hist32, int n,
                                                 int* __restrict__ start,
                                                 int* __restrict__ bsum) {
  __shared__ int wsum[16];
  int t = threadIdx.x, lane = t & 63, w = t >> 6;
  int i = blockIdx.x * 1024 + t;
  int nh4 = (n + 3) >> 2;
  size_t planeB = (size_t)nh4 * 4;
  const unsigned char* h8 = (const unsigned char*)hist32;
  int v = 0;
  if (i < n) {
#pragma unroll 8
    for (int r = 0; r < NB; ++r) v += h8[(size_t)r * planeB + i];
  }
  int x = wave_incl_scan(v, lane);
  if (lane == 63) wsum[w] = x;
  __syncthreads();
  if (w == 0 && lane < 16) {
    int s = wsum[lane];
    for (int off = 1; off < 16; off <<= 1) {
      int u = __shfl_up(s, off);
      if (lane >= off) s += u;
    }
    wsum[lane] = s;
  }
  __syncthreads();
  int woff = w ? wsum[w - 1] : 0;
  if (i < n) start[i] = x - v + woff;
  if (t == 1023) bsum[blockIdx.x] = wsum[15];
}

__global__ void k_scan_b(int* __restrict__ bsum, int nb, int* __restrict__ start, int n) {
  int lane = threadIdx.x;  // 64
  int v = (lane < nb) ? bsum[lane] : 0;
  int x = wave_incl_scan(v, lane);
  if (lane < nb) bsum[lane] = x - v;
  if (lane == nb - 1) start[n] = x;
}

// phase C: finalize start; emit per-(block,node) cursor bases
__global__ void k_scan_c(int* __restrict__ start, const int* __restrict__ bsum,
                         const unsigned* __restrict__ hist32, int n,
                         int* __restrict__ cursorp) {
  int i = blockIdx.x * blockDim.x + threadIdx.x;
  if (i >= n) return;
  int nh4 = (n + 3) >> 2;
  size_t planeB = (size_t)nh4 * 4;
  const unsigned char* h8 = (const unsigned char*)hist32;
  int s = start[i] + bsum[i >> 10];
  start[i] = s;
  int run = s;
#pragma unroll 8
  for (int r = 0; r < NB; ++r) {
    cursorp[(size_t)r * n + i] = run;
    run += h8[(size_t)r * planeB + i];
  }
}

// same NB-block edge partition as hist; rank via LDS packed-u8 atomic;
// writes three 8B records {src, eaP_l} per edge (eaP in fp32 from raw ea).
__global__ void k_scatter_lds(const int* __restrict__ src, const int* __restrict__ dst,
                              const float* __restrict__ ea, int E, int n,
                              const int* __restrict__ cursorp,
                              const float* __restrict__ P_all,
                              int2* __restrict__ m0a, int2* __restrict__ m1a,
                              int2* __restrict__ m2a) {
  extern __shared__ unsigned cnt[];
  int nh4 = (n + 3) >> 2;
  for (int i = threadIdx.x; i < nh4; i += blockDim.x) cnt[i] = 0u;
  __syncthreads();
  float P00 = P_all[0], P01 = P_all[1], P02 = P_all[2];
  float P10 = P_all[4], P11 = P_all[5], P12 = P_all[6];
  float P20 = P_all[8], P21 = P_all[9], P22 = P_all[10];
  const int* cur = cursorp + (size_t)blockIdx.x * n;
  int tid = blockIdx.x * blockDim.x + threadIdx.x;
  int stride = gridDim.x * blockDim.x;
  for (int i = tid; i < E; i += stride) {
    int d = dst[i];
    int sh = (d & 3) << 3;
    unsigned old = atomicAdd(&cnt[d >> 2], 1u << sh);
    int rank = (old >> sh) & 0xFF;
    int pos = cur[d] + rank;
    float e0 = ea[i * 3 + 0], e1 = ea[i * 3 + 1], e2 = ea[i * 3 + 2];
    int s = src[i];
    int2 r;
    r.x = s;
    r.y = __float_as_int(e0 * P00 + e1 * P01 + e2 * P02);
    m0a[pos] = r;
    r.y = __float_as_int(e0 * P10 + e1 * P11 + e2 * P12);
    m1a[pos] = r;
    r.y = __float_as_int(e0 * P20 + e1 * P21 + e2 * P22);
    m2a[pos] = r;
  }
}

__device__ __forceinline__ void param_wave(const float* __restrict__ We,
                                           const float* __restrict__ ae,
                                           const float* __restrict__ ea_sum, float invE,
                                           float* __restrict__ P, int lane) {
  float a0 = ae[lane], a1 = ae[64 + lane];
  float p0 = We[0 * 128 + lane] * a0 + We[0 * 128 + 64 + lane] * a1;
  float p1 = We[1 * 128 + lane] * a0 + We[1 * 128 + 64 + lane] * a1;
  float p2 = We[2 * 128 + lane] * a0 + We[2 * 128 + 64 + lane] * a1;
  for (int off = 32; off; off >>= 1) {
    p0 += __shfl_down(p0, off); p1 += __shfl_down(p1, off); p2 += __shfl_down(p2, off);
  }
  if (lane == 0) {
    P[0] = p0; P[1] = p1; P[2] = p2;
    P[3] = ea_sum[0] * invE * p0 + ea_sum[1] * invE * p1 + ea_sum[2] * invE * p2;
  }
}

// all three layers' P vectors (wave l -> P_all[4l..4l+3]) + zero cs0/1/2
__global__ void k_param_all(const float* __restrict__ We0, const float* __restrict__ ae0,
                            const float* __restrict__ We1, const float* __restrict__ ae1,
                            const float* __restrict__ We2, const float* __restrict__ ae2,
                            const float* __restrict__ ea_sum, float invE,
                            float* __restrict__ P_all, float* __restrict__ cs0,
                            float* __restrict__ cs1, float* __restrict__ cs2) {
  int t = threadIdx.x;  // 256
  if (t < 192) {
    int l = t >> 6, lane = t & 63;
    const float* We = l == 0 ? We0 : l == 1 ? We1 : We2;
    const float* ae = l == 0 ? ae0 : l == 1 ? ae1 : ae2;
    param_wave(We, ae, ea_sum, invE, P_all + 4 * l, lane);
  } else {
    for (int i = t - 192; i < 256; i += 64) {
      cs0[i] = 0.f; cs1[i] = 0.f; cs2[i] = 0.f;
    }
  }
}

// h[N,128] = BN(X) @ W via bf16 MFMA.  BN scale/shift computed IN-KERNEL
// from csIn (colstats of previous layer; csIn==null -> identity).
__global__ __launch_bounds__(256) void k_gemm3(
    const float* __restrict__ X, const float* __restrict__ Wm,
    const float* __restrict__ csIn, const float* __restrict__ g,
    const float* __restrict__ be, float invN,
    const float* __restrict__ as, const float* __restrict__ ad,
    const float* __restrict__ P,
    unsigned* __restrict__ hb, float* __restrict__ al_s, float* __restrict__ al_d,
    float* __restrict__ es, int n) {
  __shared__ __align__(16) unsigned short wb[128 * 136];  // 34.8 KB
  __shared__ __align__(16) unsigned short xb[64 * 136];   // 17.4 KB
  __shared__ float sc_s[128], sh_s[128];
  int t = threadIdx.x;
  int lane = t & 63;
  int w = t >> 6;
  int c16 = lane & 15;
  int kq = lane >> 4;
  if (t < 128) {
    float sc = 1.f, sh = 0.f;
    if (csIn) {
      float mu = csIn[t] * invN;
      float var = csIn[128 + t] * invN - mu * mu;
      var = var > 0.f ? var : 0.f;
      sc = g[t] * rsqrtf(var + 1e-5f);
      sh = be[t] - mu * sc;
    }
    sc_s[t] = sc; sh_s[t] = sh;
  }
  for (int i = t; i < 4096; i += 256) {
    int k = i >> 5, c4 = (i & 31) << 2;
    float4 v = ((const float4*)(Wm + k * 128))[i & 31];
    wb[(c4 + 0) * 136 + k] = f2bf(v.x);
    wb[(c4 + 1) * 136 + k] = f2bf(v.y);
    wb[(c4 + 2) * 136 + k] = f2bf(v.z);
    wb[(c4 + 3) * 136 + k] = f2bf(v.w);
  }
  float asv[8], adv[8];
#pragma unroll
  for (int ct = 0; ct < 8; ++ct) {
    asv[ct] = as[ct * 16 + c16];
    adv[ct] = ad[ct * 16 + c16];
  }
  float cself = P[3];
  int ntiles = (n + 63) >> 6;
  for (int tile = blockIdx.x; tile < ntiles; tile += gridDim.x) {
    int r0 = tile << 6;
    __syncthreads();  // protect xb vs prev epilogue; publish sc_s/sh_s/wb
    for (int i = t; i < 2048; i += 256) {
      int row = i >> 5, c4 = i & 31;
      int g2 = r0 + row;
      float4 v;
      if (g2 < n) {
        v = ((const float4*)(X + (size_t)g2 * 128))[c4];
        float4 sc = ((const float4*)sc_s)[c4];
        float4 sh = ((const float4*)sh_s)[c4];
        v.x = fmaf(v.x, sc.x, sh.x); v.y = fmaf(v.y, sc.y, sh.y);
        v.z = fmaf(v.z, sc.z, sh.z); v.w = fmaf(v.w, sc.w, sh.w);
      } else { v.x = v.y = v.z = v.w = 0.f; }
      uint2 pk;
      pk.x = (unsigned)f2bf(v.x) | ((unsigned)f2bf(v.y) << 16);
      pk.y = (unsigned)f2bf(v.z) | ((unsigned)f2bf(v.w) << 16);
      *(uint2*)(xb + row * 136 + (c4 << 2)) = pk;
    }
    __syncthreads();
    const unsigned short* xr = xb + (w * 16 + c16) * 136 + kq * 8;
    bf16x8 A[4];
#pragma unroll
    for (int kb = 0; kb < 4; ++kb) A[kb] = *(const bf16x8*)(xr + kb * 32);
    f32x4 acc[8];
#pragma unroll
    for (int ct = 0; ct < 8; ++ct) {
      const unsigned short* wr = wb + (ct * 16 + c16) * 136 + kq * 8;
      f32x4 a = {0.f, 0.f, 0.f, 0.f};
#pragma unroll
      for (int kb = 0; kb < 4; ++kb) {
        bf16x8 B = *(const bf16x8*)(wr + kb * 32);
        a = __builtin_amdgcn_mfma_f32_16x16x32_bf16(A[kb], B, a, 0, 0, 0);
      }
      acc[ct] = a;
    }
#pragma unroll
    for (int r = 0; r < 4; ++r) {
      int R = kq * 4 + r;
      float pr = 0.f, pd = 0.f;
#pragma unroll
      for (int ct = 0; ct < 8; ++ct) {
        float hv = acc[ct][r];
        xb[(w * 16 + R) * 136 + ct * 16 + c16] = f2bf(hv);
        pr = fmaf(hv, asv[ct], pr);
        pd = fmaf(hv, adv[ct], pd);
      }
      for (int off = 8; off; off >>= 1) {
        pr += __shfl_xor(pr, off);
        pd += __shfl_xor(pd, off);
      }
      int g2 = r0 + w * 16 + R;
      if (c16 == 0 && g2 < n) {
        al_s[g2] = pr; al_d[g2] = pd;
        float a = pr + pd + cself;
        a = a > 0.f ? a : 0.2f * a;
        es[g2] = __expf(a);
      }
    }
    __syncthreads();  // ensure LDS h visible (cross-lane) before flush
    for (int i = lane; i < 256; i += 64) {
      int row = i >> 4, cc = i & 15;
      int g2 = r0 + w * 16 + row;
      if (g2 < n) {
        uint4 v = *(const uint4*)(xb + (w * 16 + row) * 136 + (cc << 3));
        *(uint4*)(hb + (size_t)g2 * 64 + (cc << 2)) = v;
      }
    }
  }
}

// One wave per node; 16-lane x uint4 row gathers (4 edges/instruction) with
// in-loop alpha (R18, verified: exp hides under gather fill).
__global__ __launch_bounds__(256) void k_agg11(const int2* __restrict__ meta,
                                               const int* __restrict__ start,
                                               const unsigned* __restrict__ hb,
                                               const float* __restrict__ es,
                                               const float* __restrict__ al_s,
                                               const float* __restrict__ al_d,
                                               const float* __restrict__ bias,
                                               float* __restrict__ y,
                                               float* __restrict__ colsum,
                                               float* __restrict__ colsumsq, int n) {
  int lane = threadIdx.x & 63;
  int w = threadIdx.x >> 6;
  int grp = lane >> 4;   // 0..3: which edge of the quad this lane serves
  int sub = lane & 15;   // position within the row (16 lanes x 16B = 256B)
  int gw = (blockIdx.x * blockDim.x + threadIdx.x) >> 6;
  int nw = (gridDim.x * blockDim.x) >> 6;
  int c0 = (sub << 3) + (grp << 1);  // this lane's 2 output cols
  float2 b2 = ((const float2*)bias)[(sub << 2) + grp];
  float s0 = 0.f, s1 = 0.f, q0 = 0.f, q1 = 0.f;

#define DO_QUAD(EB)                                                          \
  {                                                                          \
    int i0 = (EB), i1 = (EB) + 1, i2 = (EB) + 2, i3 = (EB) + 3;              \
    int2 m0 = meta[i0 < e1 ? i0 : e0];                                       \
    int2 m1 = meta[i1 < e1 ? i1 : e0];                                       \
    int2 m2 = meta[i2 < e1 ? i2 : e0];                                       \
    int2 m3 = meta[i3 < e1 ? i3 : e0];                                       \
    int r0 = i0 < e1 ? m0.x : i;                                             \
    int r1 = i1 < e1 ? m1.x : i;                                             \
    int r2 = i2 < e1 ? m2.x : i;                                             \
    int r3 = i3 < e1 ? m3.x : i;                                             \
    float a0 = al_s[r0] + ad_i + __int_as_float(m0.y);                       \
    float a1 = al_s[r1] + ad_i + __int_as_float(m1.y);                       \
    float a2 = al_s[r2] + ad_i + __int_as_float(m2.y);                       \
    float a3 = al_s[r3] + ad_i + __int_as_float(m3.y);                       \
    a0 = a0 > 0.f ? a0 : 0.2f * a0;                                          \
    a1 = a1 > 0.f ? a1 : 0.2f * a1;                                          \
    a2 = a2 > 0.f ? a2 : 0.2f * a2;                                          \
    a3 = a3 > 0.f ? a3 : 0.2f * a3;                                          \
    float p0 = i0 < e1 ? __expf(a0) : 0.f;                                   \
    float p1 = i1 < e1 ? __expf(a1) : 0.f;                                   \
    float p2 = i2 < e1 ? __expf(a2) : 0.f;                                   \
    float p3 = i3 < e1 ? __expf(a3) : 0.f;                                   \
    int rr = grp == 0 ? r0 : grp == 1 ? r1 : grp == 2 ? r2 : r3;             \
    float pp = grp == 0 ? p0 : grp == 1 ? p1 : grp == 2 ? p2 : p3;           \
    uint4 gv = *(const uint4*)(hb + (size_t)rr * 64 + (sub << 2));           \
    pacc += (p0 + p1) + (p2 + p3);                                           \
    aL0 = fmaf(pp, bf_lo(gv.x), aL0); aH0 = fmaf(pp, bf_hi(gv.x), aH0);      \
    aL1 = fmaf(pp, bf_lo(gv.y), aL1); aH1 = fmaf(pp, bf_hi(gv.y), aH1);      \
    aL2 = fmaf(pp, bf_lo(gv.z), aL2); aH2 = fmaf(pp, bf_hi(gv.z), aH2);      \
    aL3 = fmaf(pp, bf_lo(gv.w), aL3); aH3 = fmaf(pp, bf_hi(gv.w), aH3);      \
  }

  for (int i = gw; i < n; i += nw) {
    int e0 = __builtin_amdgcn_readfirstlane(start[i]);
    int e1 = __builtin_amdgcn_readfirstlane(start[i + 1]);
    float eself = es[i];
    float ad_i = al_d[i];
    uint4 hv = *(const uint4*)(hb + (size_t)i * 64 + (sub << 2));
    float wself = (grp == 0) ? eself : 0.f;  // self-term counted once
    float aL0 = wself * bf_lo(hv.x), aH0 = wself * bf_hi(hv.x);
    float aL1 = wself * bf_lo(hv.y), aH1 = wself * bf_hi(hv.y);
    float aL2 = wself * bf_lo(hv.z), aH2 = wself * bf_hi(hv.z);
    float aL3 = wself * bf_lo(hv.w), aH3 = wself * bf_hi(hv.w);
    float pacc = 0.f;
    int e = e0;
    for (; e + 8 <= e1; e += 8) {  // two quads -> two gathers in flight
      DO_QUAD(e);
      DO_QUAD(e + 4);
    }
    for (; e < e1; e += 4) DO_QUAD(e);
    // combine the 4 lane-groups (bits 4,5 of lane)
    aL0 += __shfl_xor(aL0, 16); aL0 += __shfl_xor(aL0, 32);
    aH0 += __shfl_xor(aH0, 16); aH0 += __shfl_xor(aH0, 32);
    aL1 += __shfl_xor(aL1, 16); aL1 += __shfl_xor(aL1, 32);
    aH1 += __shfl_xor(aH1, 16); aH1 += __shfl_xor(aH1, 32);
    aL2 += __shfl_xor(aL2, 16); aL2 += __shfl_xor(aL2, 32);
    aH2 += __shfl_xor(aH2, 16); aH2 += __shfl_xor(aH2, 32);
    aL3 += __shfl_xor(aL3, 16); aL3 += __shfl_xor(aL3, 32);
    aH3 += __shfl_xor(aH3, 16); aH3 += __shfl_xor(aH3, 32);
    float inv = 1.0f / (eself + pacc + 1e-16f);
    float o0 = grp == 0 ? aL0 : grp == 1 ? aL1 : grp == 2 ? aL2 : aL3;
    float o1 = grp == 0 ? aH0 : grp == 1 ? aH1 : grp == 2 ? aH2 : aH3;
    o0 = fmaf(o0, inv, b2.x);
    o1 = fmaf(o1, inv, b2.y);
    o0 = o0 > 0.f ? o0 : 0.01f * o0;
    o1 = o1 > 0.f ? o1 : 0.01f * o1;
    float2 o2 = {o0, o1};
    *(float2*)(y + (size_t)i * 128 + c0) = o2;
    s0 += o0; s1 += o1;
    q0 = fmaf(o0, o0, q0); q1 = fmaf(o1, o1, q1);
  }
#undef DO_QUAD
  __shared__ float red[4][4][64];
  red[0][w][lane] = s0; red[1][w][lane] = s1; red[2][w][lane] = q0; red[3][w][lane] = q1;
  __syncthreads();
  if (w == 0) {
    for (int ww = 1; ww < 4; ++ww) {
      s0 += red[0][ww][lane]; s1 += red[1][ww][lane];
      q0 += red[2][ww][lane]; q1 += red[3][ww][lane];
    }
    atomicAdd(&colsum[c0], s0);
    atomicAdd(&colsum[c0 + 1], s1);
    atomicAdd(&colsumsq[c0], q0);
    atomicAdd(&colsumsq[c0 + 1], q1);
  }
}

// final BN: compute scale/shift from colstats in-block, then apply y -> out
__global__ __launch_bounds__(256) void k_bnapply_final(
    const float4* __restrict__ yin, const float* __restrict__ colstats,
    const float* __restrict__ g, const float* __restrict__ be, float invN,
    float4* __restrict__ yout, int total4) {
  __shared__ float sc_s[128], sh_s[128];
  int t = threadIdx.x;
  if (t < 128) {
    float mu = colstats[t] * invN;
    float var = colstats[128 + t] * invN - mu * mu;
    var = var > 0.f ? var : 0.f;
    float sc = g[t] * rsqrtf(var + 1e-5f);
    sc_s[t] = sc;
    sh_s[t] = be[t] - mu * sc;
  }
  __syncthreads();
  for (int i = blockIdx.x * blockDim.x + t; i < total4; i += gridDim.x * blockDim.x) {
    int c4 = (i & 31) << 2;
    float4 v = yin[i];
    v.x = fmaf(v.x, sc_s[c4 + 0], sh_s[c4 + 0]);
    v.y = fmaf(v.y, sc_s[c4 + 1], sh_s[c4 + 1]);
    v.z = fmaf(v.z, sc_s[c4 + 2], sh_s[c4 + 2]);
    v.w = fmaf(v.w, sc_s[c4 + 3], sh_s[c4 + 3]);
    yout[i] = v;
  }
}

extern "C" void kernel_launch(void* const* d_in, const int* in_sizes, int n_in,
                              void* d_out, int out_size, void* d_ws, size_t ws_size,
                              hipStream_t stream) {
  const float* x = (const float*)d_in[0];
  const int* eidx = (const int*)d_in[1];
  const float* ea = (const float*)d_in[3];
  const int H = 128;
  const int N = in_sizes[0] / H;
  const int E = in_sizes[1] / 2;
  const int* srcIdx = eidx;
  const int* dstIdx = eidx + E;
  const int nh4 = (N + 3) >> 2;

  char* ws = (char*)d_ws;
  size_t off = 0;
  auto alloc = [&](size_t bytes) -> void* {
    void* p = ws + off;
    off = (off + bytes + 255) & ~(size_t)255;
    return p;
  };
  int2* meta0 = (int2*)alloc((size_t)E * sizeof(int2));  // {src, eaP0}
  int2* meta1 = (int2*)alloc((size_t)E * sizeof(int2));  // {src, eaP1}
  int2* meta2 = (int2*)alloc((size_t)E * sizeof(int2));  // {src, eaP2}
  unsigned* hb = (unsigned*)alloc((size_t)N * 64 * sizeof(unsigned));  // bf16 h
  float* y = (float*)alloc((size_t)N * H * sizeof(float));
  float* al_s = (float*)alloc((size_t)N * sizeof(float));
  float* al_d = (float*)alloc((size_t)N * sizeof(float));
  float* es = (float*)alloc((size_t)N * sizeof(float));
  int* start = (int*)alloc((size_t)(N + 1) * sizeof(int));
  int* bsum = (int*)alloc(64 * sizeof(int));
  float* cs0 = (float*)alloc(256 * sizeof(float));
  float* cs1 = (float*)alloc(256 * sizeof(float));
  float* cs2 = (float*)alloc(256 * sizeof(float));
  float* ea_sum = (float*)alloc(64 * sizeof(float));
  float* P_all = (float*)alloc(16 * sizeof(float));
  unsigned* hist32 = (unsigned*)alloc((size_t)NB * nh4 * sizeof(unsigned));
  int* cursorp = (int*)alloc((size_t)NB * N * sizeof(int));

  const int nb = (N + 1023) / 1024;  // <= 64 scan_a blocks
  const float invE = 1.0f / (float)E;
  const float invN = 1.0f / (float)N;
  const size_t ldsBytes = (size_t)nh4 * sizeof(unsigned);  // ~50 KB @ N=50k

  // layer parameter pointers
  const float* Wl[3]; const float* asl[3]; const float* adl[3]; const float* Wel[3];
  const float* ael[3]; const float* bl[3]; const float* gl[3]; const float* bel[3];
  for (int l = 0; l < 3; ++l) {
    Wl[l] = (const float*)d_in[4 + 8 * l + 0];
    asl[l] = (const float*)d_in[4 + 8 * l + 1];
    adl[l] = (const float*)d_in[4 + 8 * l + 2];
    Wel[l] = (const float*)d_in[4 + 8 * l + 3];
    ael[l] = (const float*)d_in[4 + 8 * l + 4];
    bl[l] = (const float*)d_in[4 + 8 * l + 5];
    gl[l] = (const float*)d_in[4 + 8 * l + 6];
    bel[l] = (const float*)d_in[4 + 8 * l + 7];
  }

  // ---- setup: CSR sort (u8 LDS histograms, NB=64 blocks); all-layer P ----
  hipMemsetAsync(ea_sum, 0, 64 * sizeof(float), stream);
  k_hist_lds<<<NB, 256, ldsBytes, stream>>>(dstIdx, ea, E, N, hist32, ea_sum);
  k_param_all<<<1, 256, 0, stream>>>(Wel[0], ael[0], Wel[1], ael[1], Wel[2], ael[2],
                                     ea_sum, invE, P_all, cs0, cs1, cs2);
  k_scan_a<<<nb, 1024, 0, stream>>>(hist32, N, start, bsum);
  k_scan_b<<<1, 64, 0, stream>>>(bsum, nb, start, N);
  k_scan_c<<<(N + 255) / 256, 256, 0, stream>>>(start, bsum, hist32, N, cursorp);
  k_scatter_lds<<<NB, 256, ldsBytes, stream>>>(srcIdx, dstIdx, ea, E, N, cursorp,
                                               P_all, meta0, meta1, meta2);

  int2* metas[3] = {meta0, meta1, meta2};
  float* css[3] = {cs0, cs1, cs2};
  const float* X = x;
  for (int l = 0; l < 3; ++l) {
    const float* csIn = l ? css[l - 1] : nullptr;
    const float* gIn = l ? gl[l - 1] : nullptr;
    const float* beIn = l ? bel[l - 1] : nullptr;
    k_gemm3<<<512, 256, 0, stream>>>(X, Wl[l], csIn, gIn, beIn, invN,
                                     asl[l], adl[l], P_all + 4 * l,
                                     hb, al_s, al_d, es, N);
    k_agg11<<<2048, 256, 0, stream>>>(metas[l], start, hb, es, al_s, al_d, bl[l], y,
                                      css[l], css[l] + 128, N);
    X = y;
  }
  k_bnapply_final<<<384, 256, 0, stream>>>((const float4*)y, cs2, gl[2], bel[2], invN,
                                           (float4*)d_out, N * 32);
}